// Round 3
// baseline (490.081 us; speedup 1.0000x reference)
//
#include <hip/hip_runtime.h>

// VQ layer, B=16, D=64, T=8192, E=512 — bitwise numpy-fp32 argmin (frozen recipe):
//   s1 = pairwise-8 sum of z*z; G = sequential-k FMA sgemm; c2 = sequential outer
//   reduce; key = (s1 - 2*G) + c2 left-assoc; first-index strict-min scan.
// Round 3: occupancy fix. Codes split across WAVES (keeps codebook addresses
// wave-uniform -> s_load broadcast). Block = 4 waves / 128 queries:
//   wave = qhalf(bit0) x chunk(bit1); chunk 0 scans codes [0,256), chunk 1 [256,512).
// Grid 1024 blocks -> 4 waves/SIMD (was 2). Tie combine: k0<=k1 -> chunk0 (lower idx).

constexpr int Dc = 64;
constexpr int Ec = 512;
constexpr int Tc = 8192;
constexpr int Bc = 16;
constexpr int QTOT = Bc * Tc;          // 131072
constexpr int ZQ_ELEMS = Bc * Dc * Tc; // 8388608
constexpr int QPB = 128;               // queries per block
constexpr int HALF_E = 256;

__global__ __launch_bounds__(256, 4) void vq_np_kernel(
    const float* __restrict__ z,       // [B, D, T]
    const float* __restrict__ cbfull,  // [4, D, E]
    const int*   __restrict__ cbidx,
    float* __restrict__ out)           // z_q [B,D,T] ++ z_id [B,T] (float)
{
    __shared__ float s_c2[Ec];
    __shared__ float s_key[QPB];
    __shared__ int   s_idx[QPB];

    const int tid = threadIdx.x;
    const int lane = tid & 63;
    const int wave = tid >> 6;        // 0..3
    const int qhalf = wave & 1;
    const int chunk = wave >> 1;      // code chunk 0/1 (wave-uniform)
    const int qlocal = qhalf * 64 + lane;
    const int q = blockIdx.x * QPB + qlocal;
    const int b = q >> 13;
    const int t = q & (Tc - 1);

    const int ci = cbidx[0] & 3;
    const float* __restrict__ cb = cbfull + (size_t)ci * (Dc * Ec); // [D, E]

    // c2[j]: numpy outer-axis reduce -> sequential d, separate mul/add
    for (int j = tid; j < Ec; j += 256) {
        float c = cb[j];
        float acc = __fmul_rn(c, c);
        for (int d = 1; d < Dc; ++d) {
            c = cb[d * Ec + j];
            acc = __fadd_rn(acc, __fmul_rn(c, c));
        }
        s_c2[j] = acc;
    }

    // query vector -> registers (lanes consecutive in t -> coalesced)
    const float* __restrict__ zp = z + (size_t)b * (Dc * Tc) + t;
    float zv[Dc];
    #pragma unroll
    for (int d = 0; d < Dc; ++d) zv[d] = zp[(size_t)d * Tc];

    // s1: numpy pairwise_sum n=64 (8 accumulators + fixed combine tree)
    float r[8];
    #pragma unroll
    for (int u = 0; u < 8; ++u) r[u] = __fmul_rn(zv[u], zv[u]);
    #pragma unroll
    for (int i = 8; i < 64; i += 8) {
        #pragma unroll
        for (int u = 0; u < 8; ++u)
            r[u] = __fadd_rn(r[u], __fmul_rn(zv[i + u], zv[i + u]));
    }
    const float s1 = __fadd_rn(
        __fadd_rn(__fadd_rn(r[0], r[1]), __fadd_rn(r[2], r[3])),
        __fadd_rn(__fadd_rn(r[4], r[5]), __fadd_rn(r[6], r[7])));

    __syncthreads();  // s_c2 ready

    const int j0 = chunk * HALF_E;
    float best = __int_as_float(0x7f800000);
    int bestIdx = j0;

    #pragma unroll 1
    for (int jb = 0; jb < HALF_E; jb += 8) {
        float acc[8];
        #pragma unroll
        for (int u = 0; u < 8; ++u) acc[u] = 0.0f;
        #pragma unroll
        for (int d = 0; d < Dc; ++d) {
            const float zd = zv[d];
            #pragma unroll
            for (int u = 0; u < 8; ++u)
                acc[u] = __fmaf_rn(zd, cb[d * Ec + j0 + jb + u], acc[u]);
        }
        #pragma unroll
        for (int u = 0; u < 8; ++u) {
            const float key = __fadd_rn(__fsub_rn(s1, __fmul_rn(2.0f, acc[u])),
                                        s_c2[j0 + jb + u]);
            if (key < best) { best = key; bestIdx = j0 + jb + u; }
        }
    }

    // combine the two chunks: tie -> chunk 0 (strictly lower index = numpy first-index)
    if (chunk == 0) { s_key[qlocal] = best; s_idx[qlocal] = bestIdx; }
    __syncthreads();
    if (chunk == 1) {
        const float k0 = s_key[qlocal];
        const int   i0 = s_idx[qlocal];
        s_idx[qlocal] = (k0 <= best) ? i0 : bestIdx;
    }
    __syncthreads();
    const int finalIdx = s_idx[qlocal];

    // z_q[b,:,t]: each chunk-wave writes 32 of the 64 dims (coalesced per d)
    float* __restrict__ op = out + (size_t)b * (Dc * Tc) + t;
    const int dbase = chunk * 32;
    #pragma unroll
    for (int dd = 0; dd < 32; ++dd) {
        const int d = dbase + dd;
        op[(size_t)d * Tc] = cb[d * Ec + finalIdx];
    }
    if (chunk == 0) out[ZQ_ELEMS + q] = (float)finalIdx;
}

extern "C" void kernel_launch(void* const* d_in, const int* in_sizes, int n_in,
                              void* d_out, int out_size, void* d_ws, size_t ws_size,
                              hipStream_t stream) {
    const float* z      = (const float*)d_in[0];
    const float* cbfull = (const float*)d_in[1];
    const int*   cbidx  = (const int*)d_in[2];
    float* out = (float*)d_out;

    dim3 grid(QTOT / QPB), block(256);
    hipLaunchKernelGGL(vq_np_kernel, grid, block, 0, stream, z, cbfull, cbidx, out);
}

// Round 4
// 171.293 us; speedup vs baseline: 2.8611x; 2.8611x over previous
//
#include <hip/hip_runtime.h>

// VQ layer, B=16, D=64, T=8192, E=512 — bitwise numpy-fp32 argmin (frozen recipe):
//   s1 = pairwise-8 sum of z*z; G = sequential-k FMA sgemm; c2 = sequential outer
//   reduce; key = (s1 - 2*G) + c2 left-assoc; first-index strict-min scan.
// Round 4: keep the 2-way wave code-split (4 waves/SIMD occupancy), but force
// the chunk id into an SGPR via readfirstlane so the codebook addresses are
// COMPILER-PROVABLY wave-uniform -> s_load broadcast (round 3 demoted them to
// per-lane VMEM: VALUBusy 60->29, dur 208->490).

constexpr int Dc = 64;
constexpr int Ec = 512;
constexpr int Tc = 8192;
constexpr int Bc = 16;
constexpr int QTOT = Bc * Tc;          // 131072
constexpr int ZQ_ELEMS = Bc * Dc * Tc; // 8388608
constexpr int QPB = 128;               // queries per block
constexpr int HALF_E = 256;

__global__ __launch_bounds__(256, 4) void vq_np_kernel(
    const float* __restrict__ z,       // [B, D, T]
    const float* __restrict__ cbfull,  // [4, D, E]
    const int*   __restrict__ cbidx,
    float* __restrict__ out)           // z_q [B,D,T] ++ z_id [B,T] (float)
{
    __shared__ float s_c2[Ec];
    __shared__ float s_key[QPB];
    __shared__ int   s_idx[QPB];

    const int tid = threadIdx.x;
    const int lane = tid & 63;
    const int qhalf = (tid >> 6) & 1;
    // chunk: wave-uniform code-half id, forced into SGPR so the compiler can
    // prove codebook addresses uniform (s_load path).
    const int chunk = __builtin_amdgcn_readfirstlane(tid >> 7);   // 0 or 1
    const int qlocal = qhalf * 64 + lane;
    const int q = blockIdx.x * QPB + qlocal;
    const int b = q >> 13;
    const int t = q & (Tc - 1);

    const int ci = cbidx[0] & 3;
    const float* __restrict__ cb = cbfull + (size_t)ci * (Dc * Ec); // [D, E]

    // c2[j]: numpy outer-axis reduce -> sequential d, separate mul/add
    for (int j = tid; j < Ec; j += 256) {
        float c = cb[j];
        float acc = __fmul_rn(c, c);
        for (int d = 1; d < Dc; ++d) {
            c = cb[d * Ec + j];
            acc = __fadd_rn(acc, __fmul_rn(c, c));
        }
        s_c2[j] = acc;
    }

    // query vector -> registers (lanes consecutive in t -> coalesced)
    const float* __restrict__ zp = z + (size_t)b * (Dc * Tc) + t;
    float zv[Dc];
    #pragma unroll
    for (int d = 0; d < Dc; ++d) zv[d] = zp[(size_t)d * Tc];

    // s1: numpy pairwise_sum n=64 (8 accumulators + fixed combine tree)
    float r[8];
    #pragma unroll
    for (int u = 0; u < 8; ++u) r[u] = __fmul_rn(zv[u], zv[u]);
    #pragma unroll
    for (int i = 8; i < 64; i += 8) {
        #pragma unroll
        for (int u = 0; u < 8; ++u)
            r[u] = __fadd_rn(r[u], __fmul_rn(zv[i + u], zv[i + u]));
    }
    const float s1 = __fadd_rn(
        __fadd_rn(__fadd_rn(r[0], r[1]), __fadd_rn(r[2], r[3])),
        __fadd_rn(__fadd_rn(r[4], r[5]), __fadd_rn(r[6], r[7])));

    __syncthreads();  // s_c2 ready

    const float* __restrict__ cbh = cb + chunk * HALF_E;  // SGPR-offset base
    float best = __int_as_float(0x7f800000);
    int bestRel = 0;

    #pragma unroll 1
    for (int jb = 0; jb < HALF_E; jb += 8) {
        float acc[8];
        #pragma unroll
        for (int u = 0; u < 8; ++u) acc[u] = 0.0f;
        #pragma unroll
        for (int d = 0; d < Dc; ++d) {
            const float zd = zv[d];
            #pragma unroll
            for (int u = 0; u < 8; ++u)
                acc[u] = __fmaf_rn(zd, cbh[d * Ec + jb + u], acc[u]);
        }
        #pragma unroll
        for (int u = 0; u < 8; ++u) {
            const float key = __fadd_rn(__fsub_rn(s1, __fmul_rn(2.0f, acc[u])),
                                        s_c2[chunk * HALF_E + jb + u]);
            if (key < best) { best = key; bestRel = jb + u; }
        }
    }
    const int bestIdx = chunk * HALF_E + bestRel;

    // combine the two chunks: tie -> chunk 0 (lower index = numpy first-index)
    if (chunk == 0) { s_key[qlocal] = best; s_idx[qlocal] = bestIdx; }
    __syncthreads();
    if (chunk == 1) {
        const float k0 = s_key[qlocal];
        const int   i0 = s_idx[qlocal];
        s_idx[qlocal] = (k0 <= best) ? i0 : bestIdx;
    }
    __syncthreads();
    const int finalIdx = s_idx[qlocal];

    // z_q[b,:,t]: each chunk-wave writes 32 of the 64 dims (coalesced per d)
    float* __restrict__ op = out + (size_t)b * (Dc * Tc) + t;
    const int dbase = chunk * 32;
    #pragma unroll
    for (int dd = 0; dd < 32; ++dd) {
        const int d = dbase + dd;
        op[(size_t)d * Tc] = cb[d * Ec + finalIdx];
    }
    if (chunk == 0) out[ZQ_ELEMS + q] = (float)finalIdx;
}

extern "C" void kernel_launch(void* const* d_in, const int* in_sizes, int n_in,
                              void* d_out, int out_size, void* d_ws, size_t ws_size,
                              hipStream_t stream) {
    const float* z      = (const float*)d_in[0];
    const float* cbfull = (const float*)d_in[1];
    const int*   cbidx  = (const int*)d_in[2];
    float* out = (float*)d_out;

    dim3 grid(QTOT / QPB), block(256);
    hipLaunchKernelGGL(vq_np_kernel, grid, block, 0, stream, z, cbfull, cbidx, out);
}

// Round 5
// 96.978 us; speedup vs baseline: 5.0535x; 1.7663x over previous
//
#include <hip/hip_runtime.h>

// VQ layer B=16,D=64,T=8192,E=512 — MFMA prefilter + exact numpy-fp32 windowed refine.
// Frozen exact recipe (round 2, absmax 0): s1=pairwise-8; G=seq-k FMA; c2=seq outer;
// key=(s1-2G)+c2 left-assoc; first-index strict-min. Used here only for (a) c2 (always)
// and (b) rare per-query rescans where the MFMA-approx window can't separate top-2.

constexpr int Dc = 64, Ec = 512, Tc = 8192;
constexpr int QTOT = 131072, ZQ = 8388608;

using short8 = __attribute__((ext_vector_type(8))) short;
using f32x16 = __attribute__((ext_vector_type(16))) float;

__device__ __forceinline__ unsigned short bf16rn(float f) {
    unsigned u = __float_as_uint(f);
    unsigned r = u + 0x7FFFu + ((u >> 16) & 1u);
    return (unsigned short)(r >> 16);
}

// ---- prep: split codebook into bf16 hi/lo MFMA B-fragments in ws ----
// slot s = (g*4 + c)*2 + hl  (g:group of 32 codes, c:k-chunk of 16, hl:hi/lo)
// ws16[s*512 + lane*8 + i] = half( cb[16c + 8*(lane>>5) + i][32g + (lane&31)] )
__global__ void vq_prep(const float* __restrict__ cbfull, const int* __restrict__ cbidx,
                        unsigned short* __restrict__ ws16) {
    int tid = blockIdx.x * 256 + threadIdx.x;   // 4096 threads: (g,c,l)
    if (tid >= 16 * 4 * 64) return;
    int l = tid & 63, c = (tid >> 6) & 3, g = tid >> 8;
    const float* cb = cbfull + (size_t)(cbidx[0] & 3) * (Dc * Ec);
    int n = g * 32 + (l & 31);
    int kbase = c * 16 + (l >> 5) * 8;
    size_t bh = ((size_t)((g * 4 + c) * 2 + 0) * 512) + l * 8;
    size_t bl = ((size_t)((g * 4 + c) * 2 + 1) * 512) + l * 8;
    #pragma unroll
    for (int i = 0; i < 8; ++i) {
        float v = cb[(kbase + i) * Ec + n];
        unsigned short h = bf16rn(v);
        float hf = __uint_as_float((unsigned)h << 16);
        ws16[bh + i] = h;
        ws16[bl + i] = bf16rn(v - hf);
    }
}

__global__ __launch_bounds__(256) void vq_main(
    const float* __restrict__ z, const float* __restrict__ cbfull,
    const int* __restrict__ cbidx, const unsigned short* __restrict__ ws16,
    float* __restrict__ out) {
    __shared__ unsigned s_B[8192];   // 32KB: B-frag chunk, later combine scratch
    __shared__ float s_c2[Ec];
    __shared__ unsigned s_w[128];
    __shared__ int s_idx[128];

    const int tid = threadIdx.x;
    const int lane = tid & 63;
    const int wave = __builtin_amdgcn_readfirstlane(tid >> 6);  // 0..3 SGPR
    const int q0 = blockIdx.x * 128;
    const int b = q0 >> 13;
    const int t0 = q0 & (Tc - 1);
    const int col = lane & 31;
    const int hh = lane >> 5;
    const int myq = wave * 32 + col;     // local query whose A-row this lane holds
    const int t = t0 + myq;

    const int ci = cbidx[0] & 3;
    const float* __restrict__ cb = cbfull + (size_t)ci * (Dc * Ec);

    // z for A-frags: zv[c*8+i] = z[b][16c+8*hh+i][t]
    float zv[32];
    const float* zp = z + (size_t)b * Dc * Tc + t;
    #pragma unroll
    for (int c = 0; c < 4; ++c)
        #pragma unroll
        for (int i = 0; i < 8; ++i)
            zv[c * 8 + i] = zp[(size_t)(c * 16 + hh * 8 + i) * Tc];

    // c2 numpy-exact (seq outer-axis, separate mul/add) -> LDS
    for (int j = tid; j < Ec; j += 256) {
        float cc = cb[j];
        float a = __fmul_rn(cc, cc);
        for (int d = 1; d < Dc; ++d) { cc = cb[d * Ec + j]; a = __fadd_rn(a, __fmul_rn(cc, cc)); }
        s_c2[j] = a;
    }

    // s1 upper bound (any order; only used for window W)
    float s1p = 0.f;
    #pragma unroll
    for (int e = 0; e < 32; ++e) s1p = __fmaf_rn(zv[e], zv[e], s1p);
    float s1b = (s1p + __shfl_xor(s1p, 32, 64)) * 1.001f + 0.01f;
    float wf = 3.1e-7f * (s1b + 1.f) + 4.2e-6f * sqrtf(s1b) + 2.1e-5f;
    unsigned w_int = (s1b > 880.f) ? 0x7FFFFFFFu : (unsigned)(wf * 2.147483648e9f) + 512u;
    if (lane < 32) s_w[myq] = w_int;

    // A-frags: -2z split to bf16 hi/lo
    short8 uhf[4], ulf[4];
    #pragma unroll
    for (int c = 0; c < 4; ++c)
        #pragma unroll
        for (int i = 0; i < 8; ++i) {
            float f = -2.0f * zv[c * 8 + i];
            unsigned short h = bf16rn(f);
            float hf = __uint_as_float((unsigned)h << 16);
            uhf[c][i] = (short)h;
            ulf[c][i] = (short)bf16rn(f - hf);
        }

    // GEMM: 4 chunks x 4 groups; streaming per-(lane,row) min1/min2 of packed keys
    unsigned m1[16], m2[16];
    #pragma unroll
    for (int r = 0; r < 16; ++r) { m1[r] = 0xFFFFFFFFu; m2[r] = 0xFFFFFFFFu; }

    for (int chk = 0; chk < 4; ++chk) {
        __syncthreads();                       // prior chunk fully consumed
        #pragma unroll
        for (int s = 0; s < 8; ++s) {          // this wave stages 8 of 32 1KB slots
            int lslot = wave * 8 + s;
            int gs = lslot >> 3, cc = (lslot >> 1) & 3, hl = lslot & 1;
            int gslot = ((chk * 4 + gs) * 4 + cc) * 2 + hl;
            const uint4 v = *(const uint4*)(ws16 + (size_t)gslot * 512 + lane * 8);
            *(uint4*)((char*)s_B + lslot * 1024 + lane * 16) = v;
        }
        __syncthreads();

        for (int gs = 0; gs < 4; ++gs) {
            int g = chk * 4 + gs;
            short8 chf[4], clf[4];
            #pragma unroll
            for (int c = 0; c < 4; ++c) {
                chf[c] = *(const short8*)((const char*)s_B + (((gs * 4 + c) * 2 + 0) * 1024) + lane * 16);
                clf[c] = *(const short8*)((const char*)s_B + (((gs * 4 + c) * 2 + 1) * 1024) + lane * 16);
            }
            float kb = s_c2[g * 32 + col];
            f32x16 acc;
            #pragma unroll
            for (int r = 0; r < 16; ++r) acc[r] = kb;
            #pragma unroll
            for (int c = 0; c < 4; ++c) {
                acc = __builtin_amdgcn_mfma_f32_32x32x16_bf16(uhf[c], chf[c], acc, 0, 0, 0);
                acc = __builtin_amdgcn_mfma_f32_32x32x16_bf16(uhf[c], clf[c], acc, 0, 0, 0);
                acc = __builtin_amdgcn_mfma_f32_32x32x16_bf16(ulf[c], chf[c], acc, 0, 0, 0);
            }
            unsigned jj = (unsigned)(g * 32 + col);
            #pragma unroll
            for (int r = 0; r < 16; ++r) {
                // A+3 in [2,4): exponent fixed, mantissa<<9 monotone; low 9 bits = j
                unsigned key = (__float_as_uint(acc[r] + 3.0f) << 9) | jj;
                unsigned mx = key > m1[r] ? key : m1[r];
                m1[r] = key < m1[r] ? key : m1[r];
                m2[r] = mx < m2[r] ? mx : m2[r];
            }
        }
    }
    __syncthreads();   // GEMM done; s_B becomes combine scratch

    // transpose (m1,m2) -> [wave][row][col][2]
    #pragma unroll
    for (int r = 0; r < 16; ++r) {
        int row = (r & 3) + 8 * (r >> 2) + 4 * hh;   // verified 32x32 C/D mapping
        unsigned* p = s_B + (((wave * 32 + row) * 32) + col) * 2;
        p[0] = m1[r]; p[1] = m2[r];
    }
    __syncthreads();

    // per-query final: lane L -> query L>>1, half L&1 (16 cols each)
    int qq = lane >> 1, hf = lane & 1;
    const unsigned* p = s_B + (((wave * 32 + qq) * 32) + hf * 16) * 2;
    unsigned M1 = 0xFFFFFFFFu, M2 = 0xFFFFFFFFu;
    #pragma unroll
    for (int e = 0; e < 32; ++e) {
        unsigned v = p[e];
        unsigned mx = v > M1 ? v : M1;
        M1 = v < M1 ? v : M1;
        M2 = mx < M2 ? mx : M2;
    }
    {
        unsigned o1 = __shfl_xor(M1, 1, 64);
        unsigned o2 = __shfl_xor(M2, 1, 64);
        unsigned mx = M1 > o1 ? M1 : o1;
        M1 = M1 < o1 ? M1 : o1;
        M2 = M2 < o2 ? M2 : o2;
        M2 = mx < M2 ? mx : M2;
    }
    if ((lane & 1) == 0) s_idx[wave * 32 + qq] = (int)(M1 & 511u);
    unsigned wq = s_w[wave * 32 + qq];
    bool resc = ((unsigned long long)M2 <= (unsigned long long)M1 + wq);
    unsigned long long mask = __ballot(resc && ((lane & 1) == 0));

    // exact rescan (numpy-fp32, frozen recipe) for ambiguous queries
    while (mask) {
        int L = __ffsll((unsigned long long)mask) - 1; mask &= mask - 1;
        int ql = L >> 1;
        const float* zq = z + (size_t)b * Dc * Tc + (t0 + wave * 32 + ql);
        float zr[64];
        #pragma unroll
        for (int d = 0; d < 64; ++d) zr[d] = zq[(size_t)d * Tc];
        float rr[8];
        #pragma unroll
        for (int u = 0; u < 8; ++u) rr[u] = __fmul_rn(zr[u], zr[u]);
        #pragma unroll
        for (int i = 8; i < 64; i += 8)
            #pragma unroll
            for (int u = 0; u < 8; ++u)
                rr[u] = __fadd_rn(rr[u], __fmul_rn(zr[i + u], zr[i + u]));
        float s1 = __fadd_rn(__fadd_rn(__fadd_rn(rr[0], rr[1]), __fadd_rn(rr[2], rr[3])),
                             __fadd_rn(__fadd_rn(rr[4], rr[5]), __fadd_rn(rr[6], rr[7])));
        float bk = __int_as_float(0x7f800000);
        int bj = 0;
        for (int u = 0; u < 8; ++u) {
            int j = u * 64 + lane;
            float G = 0.f;
            #pragma unroll
            for (int d = 0; d < 64; ++d) G = __fmaf_rn(zr[d], cb[d * Ec + j], G);
            float key = __fadd_rn(__fsub_rn(s1, __fmul_rn(2.0f, G)), s_c2[j]);
            if (key < bk) { bk = key; bj = j; }
        }
        #pragma unroll
        for (int m = 1; m < 64; m <<= 1) {
            float pk = __shfl_xor(bk, m, 64);
            int pj = __shfl_xor(bj, m, 64);
            if (pk < bk || (pk == bk && pj < bj)) { bk = pk; bj = pj; }
        }
        if (lane == 0) s_idx[wave * 32 + ql] = bj;
    }
    __syncthreads();

    // epilogue: z_q gather (wave w owns d in [16w,16w+16)), z_id
    for (int qh = 0; qh < 2; ++qh) {
        int ql = qh * 64 + lane;
        int jj = s_idx[ql];
        int tt = t0 + ql;
        #pragma unroll
        for (int dd = 0; dd < 16; ++dd) {
            int d = wave * 16 + dd;
            out[((size_t)b * Dc + d) * Tc + tt] = cb[d * Ec + jj];
        }
        if (wave == 0) out[ZQ + q0 + ql] = (float)jj;
    }
}

extern "C" void kernel_launch(void* const* d_in, const int* in_sizes, int n_in,
                              void* d_out, int out_size, void* d_ws, size_t ws_size,
                              hipStream_t stream) {
    const float* z = (const float*)d_in[0];
    const float* cbfull = (const float*)d_in[1];
    const int* cbidx = (const int*)d_in[2];
    unsigned short* ws16 = (unsigned short*)d_ws;
    float* out = (float*)d_out;

    hipLaunchKernelGGL(vq_prep, dim3(16), dim3(256), 0, stream, cbfull, cbidx, ws16);
    hipLaunchKernelGGL(vq_main, dim3(QTOT / 128), dim3(256), 0, stream,
                       z, cbfull, cbidx, ws16, out);
}